// Round 10
// baseline (434.441 us; speedup 1.0000x reference)
//
#include <hip/hip_runtime.h>

#define N_NODES 20000
#define C 64
#define E_EDGES 320000
#define S_SPEC 64
#define R_DIM 8
#define HR 64
#define HEADS 2
#define TE 64
#define NT (E_EDGES/TE)          // 5000 blocks = 8 x 625
#define HPAD 68                  // padded bf16 row stride (k-dim)
#define INV_AVG (1.0f/16.0f)
#define NB 64                    // nodes per MFMA node-block
#define NNB ((N_NODES + NB - 1)/NB)   // 313

// out layout: node_out [0,40000) ; f_s [40000, 1320000) ; f_v [1320000, 5160000)
#define FS_OFF 40000
#define FV_OFF 1320000

typedef short bf16x4 __attribute__((ext_vector_type(4)));
typedef float f32x4  __attribute__((ext_vector_type(4)));

__device__ __forceinline__ unsigned short f2bf(float f){
  unsigned u = __float_as_uint(f);
  u += 0x7fffu + ((u >> 16) & 1u);
  return (unsigned short)(u >> 16);
}
__device__ __forceinline__ float bf2f(unsigned short b){
  return __uint_as_float(((unsigned)b) << 16);
}
__device__ __forceinline__ float phi_f(float x){
  float n = x * 0.5f;
  float s = (n > 0.0f) ? expf(-1.0f/n) : 0.0f;
  return 1.0f / (1.0f + n * s);
}

// ---------------- prep: Wr2T[n][k] = bf16(Wr2[k][n] / AVG)  (320x64) ------------------
__global__ __launch_bounds__(256) void wr2t_kernel(const float* __restrict__ Wr2,
                                                   unsigned short* __restrict__ wr2t){
  int idx = blockIdx.x*256 + threadIdx.x;      // n*64 + k
  int n = idx >> 6, k = idx & 63;
  wr2t[idx] = f2bf(Wr2[k*320 + n] * INV_AVG);
}

// ---------------- K1: node_up as bf16 MFMA GEMM, 64 nodes/block -----------------------
__global__ __launch_bounds__(256) void node_up_mfma(
    const float* __restrict__ fs, const float* __restrict__ fv,
    const float* __restrict__ Wus, const float* __restrict__ Wuv,
    ushort4* __restrict__ suv){
  __shared__ __align__(16) unsigned short A[4][NB][HPAD];   // s, vx, vy, vz  34.8 KB
  __shared__ __align__(16) unsigned short B[2][NB][HPAD];   // WusT, WuvT     17.4 KB
  const int t = threadIdx.x;
  const int n0 = blockIdx.x * NB;
  #pragma unroll
  for (int j = 0; j < 4; ++j){
    int el = (t + 256*j)*4; int row = el >> 6, c = el & 63;
    float4 v = (n0+row < N_NODES) ? *(const float4*)&fs[(size_t)(n0+row)*C + c]
                                  : (float4){0,0,0,0};
    ushort4 o; o.x=f2bf(v.x); o.y=f2bf(v.y); o.z=f2bf(v.z); o.w=f2bf(v.w);
    *(ushort4*)&A[0][row][c] = o;
  }
  #pragma unroll
  for (int j = 0; j < 16; ++j){
    int el = t + 256*j; int row = el >> 6, c = el & 63;
    float x=0,y=0,z=0;
    if (n0+row < N_NODES){
      const float* p = &fv[((size_t)(n0+row)*C + c)*3];
      x = p[0]; y = p[1]; z = p[2];
    }
    A[1][row][c] = f2bf(x); A[2][row][c] = f2bf(y); A[3][row][c] = f2bf(z);
  }
  #pragma unroll
  for (int j = 0; j < 16; ++j){
    int el = t + 256*j; int c = el >> 6, d = el & 63;
    B[0][d][c] = f2bf(Wus[c*C + d]);
    B[1][d][c] = f2bf(Wuv[c*C + d]);
  }
  __syncthreads();
  const int lane = t & 63, w = t >> 6;
  const int arow = w*16 + (lane & 15);
  const int koff = 4*(lane >> 4);
  f32x4 acc[4][4];
  #pragma unroll
  for (int a=0;a<4;a++)
    #pragma unroll
    for (int cf=0;cf<4;cf++) acc[a][cf] = (f32x4){0,0,0,0};
  #pragma unroll
  for (int kt = 0; kt < 4; ++kt){
    bf16x4 a0 = *(const bf16x4*)&A[0][arow][kt*16+koff];
    bf16x4 a1 = *(const bf16x4*)&A[1][arow][kt*16+koff];
    bf16x4 a2 = *(const bf16x4*)&A[2][arow][kt*16+koff];
    bf16x4 a3 = *(const bf16x4*)&A[3][arow][kt*16+koff];
    #pragma unroll
    for (int cf = 0; cf < 4; ++cf){
      const int brow = cf*16 + (lane & 15);
      bf16x4 b0 = *(const bf16x4*)&B[0][brow][kt*16+koff];
      bf16x4 b1 = *(const bf16x4*)&B[1][brow][kt*16+koff];
      acc[0][cf] = __builtin_amdgcn_mfma_f32_16x16x16bf16_1k(a0, b0, acc[0][cf], 0,0,0);
      acc[1][cf] = __builtin_amdgcn_mfma_f32_16x16x16bf16_1k(a1, b1, acc[1][cf], 0,0,0);
      acc[2][cf] = __builtin_amdgcn_mfma_f32_16x16x16bf16_1k(a2, b1, acc[2][cf], 0,0,0);
      acc[3][cf] = __builtin_amdgcn_mfma_f32_16x16x16bf16_1k(a3, b1, acc[3][cf], 0,0,0);
    }
  }
  #pragma unroll
  for (int i = 0; i < 4; ++i){
    int n = n0 + w*16 + (lane>>4)*4 + i;
    if (n < N_NODES){
      #pragma unroll
      for (int cf = 0; cf < 4; ++cf){
        int c = cf*16 + (lane & 15);
        ushort4 o;
        o.x = f2bf(acc[0][cf][i]); o.y = f2bf(acc[1][cf][i]);
        o.z = f2bf(acc[2][cf][i]); o.w = f2bf(acc[3][cf][i]);
        suv[(size_t)n*C + c] = o;
      }
    }
  }
}

// ---------------- edge sort passes ----------------------------------------------------
__global__ __launch_bounds__(256) void hist_kernel(const int* __restrict__ rcv, int* __restrict__ count){
  int e = blockIdx.x*256 + threadIdx.x;
  atomicAdd(&count[rcv[e]], 1);
}

__global__ __launch_bounds__(1024) void scan_kernel(const int* __restrict__ count, int* __restrict__ cursor){
  __shared__ int sums[1024];
  const int t = threadIdx.x;
  const int base = t*20;
  int s = 0;
  #pragma unroll 4
  for (int i = 0; i < 20; ++i){ int idx = base+i; if (idx < N_NODES) s += count[idx]; }
  sums[t] = s;
  __syncthreads();
  for (int off = 1; off < 1024; off <<= 1){
    int v = (t >= off) ? sums[t-off] : 0;
    __syncthreads();
    sums[t] += v;
    __syncthreads();
  }
  int run = (t > 0) ? sums[t-1] : 0;
  for (int i = 0; i < 20; ++i){
    int idx = base+i;
    if (idx < N_NODES){ cursor[idx] = run; run += count[idx]; }
  }
}

__global__ __launch_bounds__(256) void scatter_kernel(
    const int* __restrict__ snd, const int* __restrict__ rcv,
    const float* __restrict__ ev, const float* __restrict__ re,
    int* __restrict__ cursor,
    int* __restrict__ snd_s, int* __restrict__ rcv_s,
    float4* __restrict__ u_s, float* __restrict__ re_s){
  int e = blockIdx.x*256 + threadIdx.x;
  int r = rcv[e];
  int pos = atomicAdd(&cursor[r], 1);
  snd_s[pos] = snd[e];
  rcv_s[pos] = r;
  float x = ev[e*3+0], y = ev[e*3+1], z = ev[e*3+2];
  float nr = sqrtf(x*x + y*y + z*z);
  float inv = 1.0f / fmaxf(nr, 1e-9f);
  float4 u4; u4.x = x*inv; u4.y = y*inv; u4.z = z*inv; u4.w = 0.f;
  u_s[pos] = u4;
  const float4* rp = (const float4*)&re[(size_t)e*R_DIM];
  float4 ra = rp[0], rb = rp[1];
  float4* op = (float4*)&re_s[(size_t)pos*R_DIM];
  op[0] = ra; op[1] = rb;
}

// ---------------- species sort passes -------------------------------------------------
__global__ __launch_bounds__(256) void sp_hist_kernel(const int* __restrict__ sp, int* __restrict__ spcount){
  int n = blockIdx.x*256 + threadIdx.x;
  if (n < N_NODES) atomicAdd(&spcount[sp[n]], 1);
}
__global__ __launch_bounds__(64) void sp_scan_kernel(const int* __restrict__ spcount,
                                                     int* __restrict__ spoff, int* __restrict__ spcur){
  if (threadIdx.x == 0){
    int run = 0;
    for (int i = 0; i < S_SPEC; ++i){ spoff[i] = run; spcur[i] = run; run += spcount[i]; }
    spoff[S_SPEC] = run;
  }
}
__global__ __launch_bounds__(256) void sp_perm_kernel(const int* __restrict__ sp,
                                                      int* __restrict__ spcur, int* __restrict__ perm_sp){
  int n = blockIdx.x*256 + threadIdx.x;
  if (n < N_NODES){
    int pos = atomicAdd(&spcur[sp[n]], 1);
    perm_sp[pos] = n;
  }
}

// ---------------- residual GEMM: species-pure 64-row blocks, packed bf16 out ----------
// NOTE: writes resp which ALIASES the suv region; must launch AFTER edge_kernel.
__global__ __launch_bounds__(256) void residual_gemm(
    const float* __restrict__ nfs, const float* __restrict__ nfv,
    const float* __restrict__ W_rs, const float* __restrict__ W_rv,
    const int* __restrict__ spoff, const int* __restrict__ perm_sp,
    ushort4* __restrict__ resp){
  const int s = blockIdx.x >> 3;
  const int chunk = blockIdx.x & 7;
  const int base = spoff[s];
  const int cnt  = spoff[s+1] - base;
  const int r0 = chunk * NB;
  if (r0 >= cnt) return;
  const int rows = min(NB, cnt - r0);
  __shared__ __align__(16) unsigned short A[4][NB][HPAD];
  __shared__ __align__(16) unsigned short B[2][NB][HPAD];
  __shared__ int nid[NB];
  const int t = threadIdx.x;
  if (t < NB) nid[t] = (t < rows) ? perm_sp[base + r0 + t] : -1;
  __syncthreads();
  #pragma unroll
  for (int j = 0; j < 16; ++j){
    int el = t + 256*j; int row = el >> 6, c = el & 63;
    int n = nid[row];
    float sv=0, x=0, y=0, z=0;
    if (n >= 0){
      sv = nfs[(size_t)n*C + c];
      const float* p = &nfv[((size_t)n*C + c)*3];
      x = p[0]; y = p[1]; z = p[2];
    }
    A[0][row][c] = f2bf(sv); A[1][row][c] = f2bf(x);
    A[2][row][c] = f2bf(y);  A[3][row][c] = f2bf(z);
  }
  const float* Ws = W_rs + (size_t)s*C*C;
  const float* Wv = W_rv + (size_t)s*C*C;
  #pragma unroll
  for (int j = 0; j < 16; ++j){
    int el = t + 256*j; int c = el >> 6, d = el & 63;
    B[0][d][c] = f2bf(Ws[c*C + d]);
    B[1][d][c] = f2bf(Wv[c*C + d]);
  }
  __syncthreads();
  const int lane = t & 63, w = t >> 6;
  const int arow = w*16 + (lane & 15);
  const int koff = 4*(lane >> 4);
  f32x4 acc[4][4];
  #pragma unroll
  for (int a=0;a<4;a++)
    #pragma unroll
    for (int cf=0;cf<4;cf++) acc[a][cf] = (f32x4){0,0,0,0};
  #pragma unroll
  for (int kt = 0; kt < 4; ++kt){
    bf16x4 a0 = *(const bf16x4*)&A[0][arow][kt*16+koff];
    bf16x4 a1 = *(const bf16x4*)&A[1][arow][kt*16+koff];
    bf16x4 a2 = *(const bf16x4*)&A[2][arow][kt*16+koff];
    bf16x4 a3 = *(const bf16x4*)&A[3][arow][kt*16+koff];
    #pragma unroll
    for (int cf = 0; cf < 4; ++cf){
      const int brow = cf*16 + (lane & 15);
      bf16x4 b0 = *(const bf16x4*)&B[0][brow][kt*16+koff];
      bf16x4 b1 = *(const bf16x4*)&B[1][brow][kt*16+koff];
      acc[0][cf] = __builtin_amdgcn_mfma_f32_16x16x16bf16_1k(a0, b0, acc[0][cf], 0,0,0);
      acc[1][cf] = __builtin_amdgcn_mfma_f32_16x16x16bf16_1k(a1, b1, acc[1][cf], 0,0,0);
      acc[2][cf] = __builtin_amdgcn_mfma_f32_16x16x16bf16_1k(a2, b1, acc[2][cf], 0,0,0);
      acc[3][cf] = __builtin_amdgcn_mfma_f32_16x16x16bf16_1k(a3, b1, acc[3][cf], 0,0,0);
    }
  }
  #pragma unroll
  for (int i = 0; i < 4; ++i){
    int row = w*16 + (lane>>4)*4 + i;
    int n = nid[row];
    if (n >= 0){
      #pragma unroll
      for (int cf = 0; cf < 4; ++cf){
        int c = cf*16 + (lane & 15);
        ushort4 o;
        o.x = f2bf(acc[0][cf][i]); o.y = f2bf(acc[1][cf][i]);
        o.z = f2bf(acc[2][cf][i]); o.w = f2bf(acc[3][cf][i]);
        resp[(size_t)n*C + c] = o;
      }
    }
  }
}

// ---------------- K2: MFMA radial GEMM, channel-split waves (unchanged from r8) -------
__global__ __launch_bounds__(512, 6) void edge_kernel(
    const float4* __restrict__ u_s, const float* __restrict__ re_s,
    const int* __restrict__ snd_s, const int* __restrict__ rcv_s,
    const float* __restrict__ Wr1, const unsigned short* __restrict__ wr2t,
    const ushort4* __restrict__ suv,
    float* __restrict__ a_s, float* __restrict__ a_v)
{
  __shared__ __align__(16) float Wr1_l[R_DIM*HR];
  __shared__ __align__(16) unsigned short Wr2T_l[320*HPAD];

  const int t = threadIdx.x;
  const int lane = t & 63;
  const int w = t >> 6;
  const int g  = w >> 1;
  const int h2 = w & 1;
  int b = blockIdx.x;
  int xcd = b & 7, idx = b >> 3;
  const int tile = xcd * (NT >> 3) + idx;
  const int e0 = tile * TE;

  Wr1_l[t] = Wr1[t];
  #pragma unroll
  for (int j = 0; j < 10; ++j){
    int i4 = t + 512*j;
    ushort4 v4 = ((const ushort4*)wr2t)[i4];
    int el = i4*4; int n = el >> 6, k = el & 63;
    *(ushort4*)&Wr2T_l[n*HPAD + k] = v4;
  }

  const int arow = g*16 + (lane & 15);
  const int koff = 4*(lane >> 4);
  const int cl = lane & 15;
  const int ebase = g*16 + (lane >> 4)*4;
  float4 ra = ((const float4*)&re_s[(size_t)(e0 + arow)*R_DIM])[0];
  float4 rb = ((const float4*)&re_s[(size_t)(e0 + arow)*R_DIM])[1];
  float u4x[4], u4y[4], u4z[4];
  int sn4[4], rc4[4];
  #pragma unroll
  for (int i = 0; i < 4; ++i){
    int e = e0 + ebase + i;
    float4 uu = u_s[e];
    u4x[i] = uu.x; u4y[i] = uu.y; u4z[i] = uu.z;
    sn4[i] = snd_s[e];
    rc4[i] = rcv_s[e];
  }
  __syncthreads();

  bf16x4 ha[4];
  #pragma unroll
  for (int kt = 0; kt < 4; ++kt){
    short4 tmp;
    #pragma unroll
    for (int j = 0; j < 4; ++j){
      int k = kt*16 + koff + j;
      float acc = ra.x*Wr1_l[0*HR+k] + ra.y*Wr1_l[1*HR+k] + ra.z*Wr1_l[2*HR+k] + ra.w*Wr1_l[3*HR+k]
                + rb.x*Wr1_l[4*HR+k] + rb.y*Wr1_l[5*HR+k] + rb.z*Wr1_l[6*HR+k] + rb.w*Wr1_l[7*HR+k];
      float sil = acc / (1.0f + expf(-acc));
      ((unsigned short*)&tmp)[j] = f2bf(sil);
    }
    ha[kt] = *(bf16x4*)&tmp;
  }

  ushort4 gv[4][2];
  #pragma unroll
  for (int i = 0; i < 4; ++i){
    const ushort4* sp_ = &suv[(size_t)sn4[i]*C];
    #pragma unroll
    for (int kk = 0; kk < 2; ++kk) gv[i][kk] = sp_[(2*h2 + kk)*16 + cl];
  }

  f32x4 acc[10];
  #pragma unroll
  for (int lf = 0; lf < 10; ++lf) acc[lf] = (f32x4){0.f,0.f,0.f,0.f};
  #pragma unroll
  for (int kt = 0; kt < 4; ++kt){
    bf16x4 af = ha[kt];
    #pragma unroll
    for (int lf = 0; lf < 10; ++lf){
      int p = lf >> 1, kk = lf & 1;
      int n = (p*4 + 2*h2 + kk)*16 + cl;
      bf16x4 bf = *(const bf16x4*)&Wr2T_l[n*HPAD + kt*16 + koff];
      acc[lf] = __builtin_amdgcn_mfma_f32_16x16x16bf16_1k(af, bf, acc[lf], 0, 0, 0);
    }
  }

  {
    float ms[2], mv0[2], mv1[2], mv2[2];
    #pragma unroll
    for (int kk = 0; kk < 2; ++kk){ ms[kk]=0.f; mv0[kk]=0.f; mv1[kk]=0.f; mv2[kk]=0.f; }
    int cur = rc4[0];
    #pragma unroll
    for (int i = 0; i < 4; ++i){
      int rc = rc4[i];
      if (rc != cur){
        #pragma unroll
        for (int kk = 0; kk < 2; ++kk){
          int c = (2*h2 + kk)*16 + cl;
          unsafeAtomicAdd(&a_s[cur*C + c],       ms[kk]);
          unsafeAtomicAdd(&a_v[(cur*3+0)*C + c], mv0[kk]);
          unsafeAtomicAdd(&a_v[(cur*3+1)*C + c], mv1[kk]);
          unsafeAtomicAdd(&a_v[(cur*3+2)*C + c], mv2[kk]);
          ms[kk]=0.f; mv0[kk]=0.f; mv1[kk]=0.f; mv2[kk]=0.f;
        }
        cur = rc;
      }
      float u0 = u4x[i], u1 = u4y[i], u2 = u4z[i];
      #pragma unroll
      for (int kk = 0; kk < 2; ++kk){
        float se  = bf2f(gv[i][kk].x);
        float ve0 = bf2f(gv[i][kk].y);
        float ve1 = bf2f(gv[i][kk].z);
        float ve2 = bf2f(gv[i][kk].w);
        float w0 = acc[0*2+kk][i];
        float w1 = acc[1*2+kk][i];
        float w2 = acc[2*2+kk][i];
        float w3 = acc[3*2+kk][i];
        float w4 = acc[4*2+kk][i];
        float dt  = ve0*u0 + ve1*u1 + ve2*u2;
        float cr0 = ve1*u2 - ve2*u1;
        float cr1 = ve2*u0 - ve0*u2;
        float cr2 = ve0*u1 - ve1*u0;
        ms[kk]  += w0*se + w3*dt;
        mv0[kk] += w1*ve0 + w2*u0 + w4*cr0;
        mv1[kk] += w1*ve1 + w2*u1 + w4*cr1;
        mv2[kk] += w1*ve2 + w2*u2 + w4*cr2;
      }
    }
    #pragma unroll
    for (int kk = 0; kk < 2; ++kk){
      int c = (2*h2 + kk)*16 + cl;
      unsafeAtomicAdd(&a_s[cur*C + c],       ms[kk]);
      unsafeAtomicAdd(&a_v[(cur*3+0)*C + c], mv0[kk]);
      unsafeAtomicAdd(&a_v[(cur*3+1)*C + c], mv1[kk]);
      unsafeAtomicAdd(&a_v[(cur*3+2)*C + c], mv2[kk]);
    }
  }
}

// ---------------- K3: node_post as two bf16 MFMA GEMMs + elementwise ------------------
__global__ __launch_bounds__(256) void node_post_mfma(
    const float* __restrict__ a_s, const float* __restrict__ a_v,
    const int* __restrict__ species,
    const float* __restrict__ W_ds, const float* __restrict__ W_dv,
    const float* __restrict__ w1s, const float* __restrict__ w1v,
    const float* __restrict__ w2ss, const float* __restrict__ w2vv, const float* __restrict__ w2sv,
    const float* __restrict__ W_ps, const float* __restrict__ W_pv,
    const ushort4* __restrict__ resp,
    const float* __restrict__ w_read, float* __restrict__ out)
{
  __shared__ __align__(16) unsigned short A[4][NB][HPAD];
  __shared__ __align__(16) unsigned short B[4][NB][HPAD];
  __shared__ int spl[NB];
  const int t = threadIdx.x;
  const int n0 = blockIdx.x * NB;
  #pragma unroll
  for (int j = 0; j < 4; ++j){
    int el = (t + 256*j)*4; int row = el >> 6, c = el & 63;
    bool ok = (n0+row < N_NODES);
    float4 v0 = ok ? *(const float4*)&a_s[(size_t)(n0+row)*C + c] : (float4){0,0,0,0};
    ushort4 o0; o0.x=f2bf(v0.x); o0.y=f2bf(v0.y); o0.z=f2bf(v0.z); o0.w=f2bf(v0.w);
    *(ushort4*)&A[0][row][c] = o0;
    #pragma unroll
    for (int x = 0; x < 3; ++x){
      float4 v = ok ? *(const float4*)&a_v[((size_t)(n0+row)*3 + x)*C + c] : (float4){0,0,0,0};
      ushort4 o; o.x=f2bf(v.x); o.y=f2bf(v.y); o.z=f2bf(v.z); o.w=f2bf(v.w);
      *(ushort4*)&A[1+x][row][c] = o;
    }
  }
  #pragma unroll
  for (int j = 0; j < 16; ++j){
    int el = t + 256*j; int c = el >> 6, d = el & 63;
    B[0][d][c] = f2bf(W_ds[c*C + d]);
    B[1][d][c] = f2bf(W_dv[c*C + d]);
    B[2][d][c] = f2bf(W_ps[c*C + d]);
    B[3][d][c] = f2bf(W_pv[c*C + d]);
  }
  if (t < NB) spl[t] = (n0 + t < N_NODES) ? species[n0 + t] : 0;
  __syncthreads();

  const int lane = t & 63, w = t >> 6;
  const int arow = w*16 + (lane & 15);
  const int koff = 4*(lane >> 4);
  const int cl = lane & 15;

  // GEMM1: down-projection
  f32x4 acc1[4][4];
  #pragma unroll
  for (int a=0;a<4;a++)
    #pragma unroll
    for (int cf=0;cf<4;cf++) acc1[a][cf] = (f32x4){0,0,0,0};
  #pragma unroll
  for (int kt = 0; kt < 4; ++kt){
    bf16x4 a0 = *(const bf16x4*)&A[0][arow][kt*16+koff];
    bf16x4 a1 = *(const bf16x4*)&A[1][arow][kt*16+koff];
    bf16x4 a2 = *(const bf16x4*)&A[2][arow][kt*16+koff];
    bf16x4 a3 = *(const bf16x4*)&A[3][arow][kt*16+koff];
    #pragma unroll
    for (int cf = 0; cf < 4; ++cf){
      const int brow = cf*16 + (lane & 15);
      bf16x4 b0 = *(const bf16x4*)&B[0][brow][kt*16+koff];
      bf16x4 b1 = *(const bf16x4*)&B[1][brow][kt*16+koff];
      acc1[0][cf] = __builtin_amdgcn_mfma_f32_16x16x16bf16_1k(a0, b0, acc1[0][cf], 0,0,0);
      acc1[1][cf] = __builtin_amdgcn_mfma_f32_16x16x16bf16_1k(a1, b1, acc1[1][cf], 0,0,0);
      acc1[2][cf] = __builtin_amdgcn_mfma_f32_16x16x16bf16_1k(a2, b1, acc1[2][cf], 0,0,0);
      acc1[3][cf] = __builtin_amdgcn_mfma_f32_16x16x16bf16_1k(a3, b1, acc1[3][cf], 0,0,0);
    }
  }
  // product basis -> write p back into A (wave-private rows)
  #pragma unroll
  for (int i = 0; i < 4; ++i){
    int row = w*16 + (lane>>4)*4 + i;
    int sp = spl[row];
    #pragma unroll
    for (int cf = 0; cf < 4; ++cf){
      int c = cf*16 + cl;
      float bs = acc1[0][cf][i], bv0 = acc1[1][cf][i], bv1 = acc1[2][cf][i], bv2 = acc1[3][cf][i];
      float vv = bv0*bv0 + bv1*bv1 + bv2*bv2;
      float ps = w1s[sp*C+c]*bs + w2ss[sp*C+c]*bs*bs + w2vv[sp*C+c]*vv;
      float c1v = w1v[sp*C+c], c2sv = w2sv[sp*C+c];
      A[0][row][c] = f2bf(ps);
      A[1][row][c] = f2bf(c1v*bv0 + c2sv*bs*bv0);
      A[2][row][c] = f2bf(c1v*bv1 + c2sv*bs*bv1);
      A[3][row][c] = f2bf(c1v*bv2 + c2sv*bs*bv2);
    }
  }
  __syncthreads();   // insurance: ensure p writes visible before GEMM2 reads
  // GEMM2: prod-projection
  f32x4 acc2[4][4];
  #pragma unroll
  for (int a=0;a<4;a++)
    #pragma unroll
    for (int cf=0;cf<4;cf++) acc2[a][cf] = (f32x4){0,0,0,0};
  #pragma unroll
  for (int kt = 0; kt < 4; ++kt){
    bf16x4 a0 = *(const bf16x4*)&A[0][arow][kt*16+koff];
    bf16x4 a1 = *(const bf16x4*)&A[1][arow][kt*16+koff];
    bf16x4 a2 = *(const bf16x4*)&A[2][arow][kt*16+koff];
    bf16x4 a3 = *(const bf16x4*)&A[3][arow][kt*16+koff];
    #pragma unroll
    for (int cf = 0; cf < 4; ++cf){
      const int brow = cf*16 + (lane & 15);
      bf16x4 b2 = *(const bf16x4*)&B[2][brow][kt*16+koff];
      bf16x4 b3 = *(const bf16x4*)&B[3][brow][kt*16+koff];
      acc2[0][cf] = __builtin_amdgcn_mfma_f32_16x16x16bf16_1k(a0, b2, acc2[0][cf], 0,0,0);
      acc2[1][cf] = __builtin_amdgcn_mfma_f32_16x16x16bf16_1k(a1, b3, acc2[1][cf], 0,0,0);
      acc2[2][cf] = __builtin_amdgcn_mfma_f32_16x16x16bf16_1k(a2, b3, acc2[2][cf], 0,0,0);
      acc2[3][cf] = __builtin_amdgcn_mfma_f32_16x16x16bf16_1k(a3, b3, acc2[3][cf], 0,0,0);
    }
  }
  // soft-norm + residual + outputs + readout
  float fsv_r[4][4];
  #pragma unroll
  for (int i = 0; i < 4; ++i){
    int row = w*16 + (lane>>4)*4 + i;
    int n = n0 + row;
    bool ok = (n < N_NODES);
    #pragma unroll
    for (int cf = 0; cf < 4; ++cf){
      int c = cf*16 + cl;
      float qs = acc2[0][cf][i], qv0 = acc2[1][cf][i], qv1 = acc2[2][cf][i], qv2 = acc2[3][cf][i];
      float rs = 0, rv0 = 0, rv1 = 0, rv2 = 0;
      if (ok){
        ushort4 rp = resp[(size_t)n*C + c];
        rs  = bf2f(rp.x); rv0 = bf2f(rp.y); rv1 = bf2f(rp.z); rv2 = bf2f(rp.w);
      }
      float fsv = qs * phi_f(fabsf(qs)) + rs;
      float nv = sqrtf(qv0*qv0 + qv1*qv1 + qv2*qv2);
      float ph = phi_f(nv);
      float fv0 = qv0*ph + rv0;
      float fv1 = qv1*ph + rv1;
      float fv2 = qv2*ph + rv2;
      fsv_r[i][cf] = fsv;
      if (ok){
        out[FS_OFF + (size_t)n*C + c] = fsv;
        float* fvo = &out[FV_OFF + ((size_t)n*C + c)*3];
        fvo[0] = fv0; fvo[1] = fv1; fvo[2] = fv2;
      }
    }
  }
  #pragma unroll
  for (int h = 0; h < HEADS; ++h){
    #pragma unroll
    for (int i = 0; i < 4; ++i){
      int row = w*16 + (lane>>4)*4 + i;
      int n = n0 + row;
      float tacc = 0.f;
      #pragma unroll
      for (int cf = 0; cf < 4; ++cf)
        tacc += fsv_r[i][cf] * w_read[h*C + cf*16 + cl];
      tacc += __shfl_xor(tacc, 1);
      tacc += __shfl_xor(tacc, 2);
      tacc += __shfl_xor(tacc, 4);
      tacc += __shfl_xor(tacc, 8);
      if (cl == 0 && n < N_NODES) out[(size_t)n*HEADS + h] = tacc;
    }
  }
}

extern "C" void kernel_launch(void* const* d_in, const int* in_sizes, int n_in,
                              void* d_out, int out_size, void* d_ws, size_t ws_size,
                              hipStream_t stream)
{
  const float* ev   = (const float*)d_in[0];
  const float* nfs  = (const float*)d_in[1];
  const float* nfv  = (const float*)d_in[2];
  const float* re   = (const float*)d_in[3];
  const int*   spec = (const int*)d_in[4];
  const int*   snd  = (const int*)d_in[5];
  const int*   rcv  = (const int*)d_in[6];
  const float* W_rs = (const float*)d_in[7];
  const float* W_rv = (const float*)d_in[8];
  const float* Wus  = (const float*)d_in[9];
  const float* Wuv  = (const float*)d_in[10];
  const float* Wr1  = (const float*)d_in[11];
  const float* Wr2  = (const float*)d_in[12];
  const float* Wds  = (const float*)d_in[13];
  const float* Wdv  = (const float*)d_in[14];
  const float* w1s  = (const float*)d_in[15];
  const float* w1v  = (const float*)d_in[16];
  const float* w2ss = (const float*)d_in[17];
  const float* w2vv = (const float*)d_in[18];
  const float* w2sv = (const float*)d_in[19];
  const float* Wps  = (const float*)d_in[20];
  const float* Wpv  = (const float*)d_in[21];
  const float* wrd  = (const float*)d_in[22];

  float* out = (float*)d_out;
  float* ws  = (float*)d_ws;
  // ws layout (f32 units). NOTE: resp ALIASES suv (edge_kernel is the last suv reader,
  // residual_gemm runs after it). Total ≈ 48.9 MB.
  ushort4* suv  = (ushort4*)ws;             // 2,560,000 f32-equiv
  ushort4* resp = (ushort4*)ws;             // alias (written after edge_kernel)
  float*   a_s  = ws + 2560000;             // 1,280,000
  float*   a_v  = ws + 3840000;             // 3,840,000 -> 7,680,000
  int*    count = (int*)(ws + 7680000);     // 20,000
  int*    cursr = (int*)(ws + 7700000);     // 20,000
  int*    snd_s = (int*)(ws + 7720000);     // 320,000
  int*    rcv_s = (int*)(ws + 8040000);     // 320,000
  float4* u_s   = (float4*)(ws + 8360000);  // 1,280,000 -> 9,640,000
  float*  re_s  = ws + 9640000;             // 2,560,000 -> 12,200,000
  unsigned short* wr2t = (unsigned short*)(ws + 12200000);  // 10,240 f32 -> 12,210,240
  int*   spcount= (int*)(ws + 12210240);    // 64
  int*   spoff  = (int*)(ws + 12210304);    // 65
  int*   spcur  = (int*)(ws + 12210432);    // 64
  int*   perm_sp= (int*)(ws + 12210496);    // 20,000 -> 12,230,496

  hipMemsetAsync(a_s, 0, (size_t)5120000*sizeof(float), stream);   // a_s + a_v
  hipMemsetAsync(count, 0, (size_t)N_NODES*sizeof(int), stream);
  hipMemsetAsync(spcount, 0, (size_t)S_SPEC*sizeof(int), stream);

  wr2t_kernel<<<(320*64)/256, 256, 0, stream>>>(Wr2, wr2t);
  node_up_mfma<<<NNB, 256, 0, stream>>>(nfs, nfv, Wus, Wuv, suv);
  hist_kernel<<<E_EDGES/256, 256, 0, stream>>>(rcv, count);
  scan_kernel<<<1, 1024, 0, stream>>>(count, cursr);
  scatter_kernel<<<E_EDGES/256, 256, 0, stream>>>(snd, rcv, ev, re, cursr,
                                                  snd_s, rcv_s, u_s, re_s);
  sp_hist_kernel<<<(N_NODES+255)/256, 256, 0, stream>>>(spec, spcount);
  sp_scan_kernel<<<1, 64, 0, stream>>>(spcount, spoff, spcur);
  sp_perm_kernel<<<(N_NODES+255)/256, 256, 0, stream>>>(spec, spcur, perm_sp);
  edge_kernel<<<NT, 512, 0, stream>>>(u_s, re_s, snd_s, rcv_s, Wr1, wr2t,
                                      suv, a_s, a_v);
  residual_gemm<<<S_SPEC*8, 256, 0, stream>>>(nfs, nfv, W_rs, W_rv, spoff, perm_sp,
                                              resp);
  node_post_mfma<<<NNB, 256, 0, stream>>>(a_s, a_v, spec, Wds, Wdv,
      w1s, w1v, w2ss, w2vv, w2sv, Wps, Wpv, resp, wrd, out);
}

// Round 11
// 399.785 us; speedup vs baseline: 1.0867x; 1.0867x over previous
//
#include <hip/hip_runtime.h>

#define N_NODES 20000
#define C 64
#define E_EDGES 320000
#define S_SPEC 64
#define R_DIM 8
#define HR 64
#define HEADS 2
#define TE 64
#define NPAIR (E_EDGES/128)      // 2500 blocks, 2 tiles (128 edges) each
#define HPAD 68                  // padded bf16 row stride (k-dim)
#define INV_AVG (1.0f/16.0f)

// out layout: node_out [0,40000) ; f_s [40000, 1320000) ; f_v [1320000, 5160000)
#define FS_OFF 40000
#define FV_OFF 1320000

typedef short bf16x4 __attribute__((ext_vector_type(4)));
typedef float f32x4  __attribute__((ext_vector_type(4)));

__device__ __forceinline__ unsigned short f2bf(float f){
  unsigned u = __float_as_uint(f);
  u += 0x7fffu + ((u >> 16) & 1u);
  return (unsigned short)(u >> 16);
}
__device__ __forceinline__ float bf2f(unsigned short b){
  return __uint_as_float(((unsigned)b) << 16);
}
__device__ __forceinline__ float phi_f(float x){
  float n = x * 0.5f;
  float s = (n > 0.0f) ? expf(-1.0f/n) : 0.0f;
  return 1.0f / (1.0f + n * s);
}

// ---------------- prep: Wr2T[n][k] = bf16(Wr2[k][n] / AVG)  (320x64) ------------------
__global__ __launch_bounds__(256) void wr2t_kernel(const float* __restrict__ Wr2,
                                                   unsigned short* __restrict__ wr2t){
  int idx = blockIdx.x*256 + threadIdx.x;      // n*64 + k
  int n = idx >> 6, k = idx & 63;
  wr2t[idx] = f2bf(Wr2[k*320 + n] * INV_AVG);
}

// ---------------- K1: up-projection, writes packed bf16 suv[n][c] = {s,v0,v1,v2} ------
__global__ __launch_bounds__(256) void node_up_kernel(
    const float* __restrict__ fs, const float* __restrict__ fv,
    const float* __restrict__ Wus, const float* __restrict__ Wuv,
    ushort4* __restrict__ suv){
  const int ni = threadIdx.x >> 6;
  const int d  = threadIdx.x & 63;
  const int n  = blockIdx.x*4 + ni;
  __shared__ float s_l[4][C];
  __shared__ float v_l[4][3][C];
  s_l[ni][d] = fs[n*C + d];
  #pragma unroll
  for (int x = 0; x < 3; ++x) v_l[ni][x][d] = fv[(n*C + d)*3 + x];
  __syncthreads();
  float as = 0.f, a0 = 0.f, a1 = 0.f, a2 = 0.f;
  #pragma unroll 4
  for (int c = 0; c < C; ++c){
    float wsv = Wus[c*C + d];
    float wvv = Wuv[c*C + d];
    as += s_l[ni][c] * wsv;
    a0 += v_l[ni][0][c] * wvv;
    a1 += v_l[ni][1][c] * wvv;
    a2 += v_l[ni][2][c] * wvv;
  }
  ushort4 o;
  o.x = f2bf(as); o.y = f2bf(a0); o.z = f2bf(a1); o.w = f2bf(a2);
  suv[(size_t)n*C + d] = o;
}

// ---------------- sort pass A: histogram of receivers ---------------------------------
__global__ __launch_bounds__(256) void hist_kernel(const int* __restrict__ rcv, int* __restrict__ count){
  int e = blockIdx.x*256 + threadIdx.x;
  atomicAdd(&count[rcv[e]], 1);
}

// ---------------- sort pass B: exclusive scan over 20000 counts (1 block) -------------
__global__ __launch_bounds__(1024) void scan_kernel(const int* __restrict__ count, int* __restrict__ cursor){
  __shared__ int sums[1024];
  const int t = threadIdx.x;
  const int base = t*20;
  int s = 0;
  #pragma unroll 4
  for (int i = 0; i < 20; ++i){ int idx = base+i; if (idx < N_NODES) s += count[idx]; }
  sums[t] = s;
  __syncthreads();
  for (int off = 1; off < 1024; off <<= 1){
    int v = (t >= off) ? sums[t-off] : 0;
    __syncthreads();
    sums[t] += v;
    __syncthreads();
  }
  int run = (t > 0) ? sums[t-1] : 0;
  for (int i = 0; i < 20; ++i){
    int idx = base+i;
    if (idx < N_NODES){ cursor[idx] = run; run += count[idx]; }
  }
}

// ---------------- sort pass C: scatter into sorted arrays, u pre-normalized ----------
__global__ __launch_bounds__(256) void scatter_kernel(
    const int* __restrict__ snd, const int* __restrict__ rcv,
    const float* __restrict__ ev, const float* __restrict__ re,
    int* __restrict__ cursor,
    int* __restrict__ snd_s, int* __restrict__ rcv_s,
    float4* __restrict__ u_s, float* __restrict__ re_s){
  int e = blockIdx.x*256 + threadIdx.x;
  int r = rcv[e];
  int pos = atomicAdd(&cursor[r], 1);
  snd_s[pos] = snd[e];
  rcv_s[pos] = r;
  float x = ev[e*3+0], y = ev[e*3+1], z = ev[e*3+2];
  float nr = sqrtf(x*x + y*y + z*z);
  float inv = 1.0f / fmaxf(nr, 1e-9f);
  float4 u4; u4.x = x*inv; u4.y = y*inv; u4.z = z*inv; u4.w = 0.f;
  u_s[pos] = u4;
  const float4* rp = (const float4*)&re[(size_t)e*R_DIM];
  float4 ra = rp[0], rb = rp[1];
  float4* op = (float4*)&re_s[(size_t)pos*R_DIM];
  op[0] = ra; op[1] = rb;
}

// ---------------- K2: MFMA radial GEMM, 2-tile software pipeline ----------------------
// 8 waves = 4 edge-groups x 2 column-halves (as r8); each block runs 2 consecutive
// 64-edge tiles sharing one Wr2T staging. Gathers issued >=700cy before consumption.
__global__ __launch_bounds__(512, 4) void edge_kernel(
    const float4* __restrict__ u_s, const float* __restrict__ re_s,
    const int* __restrict__ snd_s, const int* __restrict__ rcv_s,
    const float* __restrict__ Wr1, const unsigned short* __restrict__ wr2t,
    const ushort4* __restrict__ suv,
    float* __restrict__ a_s, float* __restrict__ a_v)
{
  __shared__ __align__(16) float Wr1_l[R_DIM*HR];            // 2 KB
  __shared__ __align__(16) unsigned short Wr2T_l[320*HPAD];  // 43.5 KB

  const int t = threadIdx.x;
  const int lane = t & 63;
  const int w = t >> 6;
  const int g  = w >> 1;                // edge-group 0..3
  const int h2 = w & 1;                 // column half
  // bijective XCD swizzle over 2500 pairs (2500 = 8*312 + 4)
  int b = blockIdx.x;
  int xcd = b & 7, idx = b >> 3;
  const int q = NPAIR >> 3, r = NPAIR & 7;
  int pair = (xcd < r ? xcd*(q+1) : r*(q+1) + (xcd-r)*q) + idx;
  const int e0A = pair * 128;
  const int e0B = e0A + 64;

  // ---- stage Wr1, Wr2T ----
  Wr1_l[t] = Wr1[t];
  #pragma unroll
  for (int j = 0; j < 10; ++j){
    int i4 = t + 512*j;
    ushort4 v4 = ((const ushort4*)wr2t)[i4];
    int el = i4*4; int n = el >> 6, k = el & 63;
    *(ushort4*)&Wr2T_l[n*HPAD + k] = v4;
  }

  const int arow = g*16 + (lane & 15);
  const int koff = 4*(lane >> 4);
  const int cl = lane & 15;
  const int ebase = g*16 + (lane >> 4)*4;

  // ---- tile A state + gather issue (covered by barrier + haA + mfmaA) ----
  float4 raA = ((const float4*)&re_s[(size_t)(e0A + arow)*R_DIM])[0];
  float4 rbA = ((const float4*)&re_s[(size_t)(e0A + arow)*R_DIM])[1];
  float uxA[4], uyA[4], uzA[4]; int snA[4], rcA[4];
  #pragma unroll
  for (int i = 0; i < 4; ++i){
    int e = e0A + ebase + i;
    float4 uu = u_s[e];
    uxA[i]=uu.x; uyA[i]=uu.y; uzA[i]=uu.z;
    snA[i]=snd_s[e]; rcA[i]=rcv_s[e];
  }
  ushort4 gvA[4][2];
  #pragma unroll
  for (int i = 0; i < 4; ++i){
    const ushort4* sp_ = &suv[(size_t)snA[i]*C];
    #pragma unroll
    for (int kk = 0; kk < 2; ++kk) gvA[i][kk] = sp_[(2*h2 + kk)*16 + cl];
  }
  __syncthreads();   // Wr2T ready

  // ---- haA ----
  bf16x4 haA[4];
  #pragma unroll
  for (int kt = 0; kt < 4; ++kt){
    short4 tmp;
    #pragma unroll
    for (int j = 0; j < 4; ++j){
      int k = kt*16 + koff + j;
      float acc = raA.x*Wr1_l[0*HR+k] + raA.y*Wr1_l[1*HR+k] + raA.z*Wr1_l[2*HR+k] + raA.w*Wr1_l[3*HR+k]
                + rbA.x*Wr1_l[4*HR+k] + rbA.y*Wr1_l[5*HR+k] + rbA.z*Wr1_l[6*HR+k] + rbA.w*Wr1_l[7*HR+k];
      float sil = acc / (1.0f + expf(-acc));
      ((unsigned short*)&tmp)[j] = f2bf(sil);
    }
    haA[kt] = *(bf16x4*)&tmp;
  }

  // ---- tile B state loads (latency covered by mfmaA) ----
  float4 raB = ((const float4*)&re_s[(size_t)(e0B + arow)*R_DIM])[0];
  float4 rbB = ((const float4*)&re_s[(size_t)(e0B + arow)*R_DIM])[1];
  float uxB[4], uyB[4], uzB[4]; int snB[4], rcB[4];
  #pragma unroll
  for (int i = 0; i < 4; ++i){
    int e = e0B + ebase + i;
    float4 uu = u_s[e];
    uxB[i]=uu.x; uyB[i]=uu.y; uzB[i]=uu.z;
    snB[i]=snd_s[e]; rcB[i]=rcv_s[e];
  }

  // ---- mfmaA ----
  f32x4 accA[10];
  #pragma unroll
  for (int lf = 0; lf < 10; ++lf) accA[lf] = (f32x4){0.f,0.f,0.f,0.f};
  #pragma unroll
  for (int kt = 0; kt < 4; ++kt){
    bf16x4 af = haA[kt];
    #pragma unroll
    for (int lf = 0; lf < 10; ++lf){
      int p = lf >> 1, kk = lf & 1;
      int n = (p*4 + 2*h2 + kk)*16 + cl;
      bf16x4 bf = *(const bf16x4*)&Wr2T_l[n*HPAD + kt*16 + koff];
      accA[lf] = __builtin_amdgcn_mfma_f32_16x16x16bf16_1k(af, bf, accA[lf], 0, 0, 0);
    }
  }

  // ---- tile B gather issue (latency covered by messagesA + haB + mfmaB) ----
  ushort4 gvB[4][2];
  #pragma unroll
  for (int i = 0; i < 4; ++i){
    const ushort4* sp_ = &suv[(size_t)snB[i]*C];
    #pragma unroll
    for (int kk = 0; kk < 2; ++kk) gvB[i][kk] = sp_[(2*h2 + kk)*16 + cl];
  }

  // ---- messages A ----
  {
    float ms[2], mv0[2], mv1[2], mv2[2];
    #pragma unroll
    for (int kk = 0; kk < 2; ++kk){ ms[kk]=0.f; mv0[kk]=0.f; mv1[kk]=0.f; mv2[kk]=0.f; }
    int cur = rcA[0];
    #pragma unroll
    for (int i = 0; i < 4; ++i){
      int rc = rcA[i];
      if (rc != cur){
        #pragma unroll
        for (int kk = 0; kk < 2; ++kk){
          int c = (2*h2 + kk)*16 + cl;
          unsafeAtomicAdd(&a_s[cur*C + c],       ms[kk]);
          unsafeAtomicAdd(&a_v[(cur*3+0)*C + c], mv0[kk]);
          unsafeAtomicAdd(&a_v[(cur*3+1)*C + c], mv1[kk]);
          unsafeAtomicAdd(&a_v[(cur*3+2)*C + c], mv2[kk]);
          ms[kk]=0.f; mv0[kk]=0.f; mv1[kk]=0.f; mv2[kk]=0.f;
        }
        cur = rc;
      }
      float u0 = uxA[i], u1 = uyA[i], u2 = uzA[i];
      #pragma unroll
      for (int kk = 0; kk < 2; ++kk){
        float se  = bf2f(gvA[i][kk].x);
        float ve0 = bf2f(gvA[i][kk].y);
        float ve1 = bf2f(gvA[i][kk].z);
        float ve2 = bf2f(gvA[i][kk].w);
        float w0 = accA[0*2+kk][i];
        float w1 = accA[1*2+kk][i];
        float w2 = accA[2*2+kk][i];
        float w3 = accA[3*2+kk][i];
        float w4 = accA[4*2+kk][i];
        float dt  = ve0*u0 + ve1*u1 + ve2*u2;
        float cr0 = ve1*u2 - ve2*u1;
        float cr1 = ve2*u0 - ve0*u2;
        float cr2 = ve0*u1 - ve1*u0;
        ms[kk]  += w0*se + w3*dt;
        mv0[kk] += w1*ve0 + w2*u0 + w4*cr0;
        mv1[kk] += w1*ve1 + w2*u1 + w4*cr1;
        mv2[kk] += w1*ve2 + w2*u2 + w4*cr2;
      }
    }
    #pragma unroll
    for (int kk = 0; kk < 2; ++kk){
      int c = (2*h2 + kk)*16 + cl;
      unsafeAtomicAdd(&a_s[cur*C + c],       ms[kk]);
      unsafeAtomicAdd(&a_v[(cur*3+0)*C + c], mv0[kk]);
      unsafeAtomicAdd(&a_v[(cur*3+1)*C + c], mv1[kk]);
      unsafeAtomicAdd(&a_v[(cur*3+2)*C + c], mv2[kk]);
    }
  }

  // ---- haB + mfmaB ----
  bf16x4 haB[4];
  #pragma unroll
  for (int kt = 0; kt < 4; ++kt){
    short4 tmp;
    #pragma unroll
    for (int j = 0; j < 4; ++j){
      int k = kt*16 + koff + j;
      float acc = raB.x*Wr1_l[0*HR+k] + raB.y*Wr1_l[1*HR+k] + raB.z*Wr1_l[2*HR+k] + raB.w*Wr1_l[3*HR+k]
                + rbB.x*Wr1_l[4*HR+k] + rbB.y*Wr1_l[5*HR+k] + rbB.z*Wr1_l[6*HR+k] + rbB.w*Wr1_l[7*HR+k];
      float sil = acc / (1.0f + expf(-acc));
      ((unsigned short*)&tmp)[j] = f2bf(sil);
    }
    haB[kt] = *(bf16x4*)&tmp;
  }
  f32x4 accB[10];
  #pragma unroll
  for (int lf = 0; lf < 10; ++lf) accB[lf] = (f32x4){0.f,0.f,0.f,0.f};
  #pragma unroll
  for (int kt = 0; kt < 4; ++kt){
    bf16x4 af = haB[kt];
    #pragma unroll
    for (int lf = 0; lf < 10; ++lf){
      int p = lf >> 1, kk = lf & 1;
      int n = (p*4 + 2*h2 + kk)*16 + cl;
      bf16x4 bf = *(const bf16x4*)&Wr2T_l[n*HPAD + kt*16 + koff];
      accB[lf] = __builtin_amdgcn_mfma_f32_16x16x16bf16_1k(af, bf, accB[lf], 0, 0, 0);
    }
  }

  // ---- messages B ----
  {
    float ms[2], mv0[2], mv1[2], mv2[2];
    #pragma unroll
    for (int kk = 0; kk < 2; ++kk){ ms[kk]=0.f; mv0[kk]=0.f; mv1[kk]=0.f; mv2[kk]=0.f; }
    int cur = rcB[0];
    #pragma unroll
    for (int i = 0; i < 4; ++i){
      int rc = rcB[i];
      if (rc != cur){
        #pragma unroll
        for (int kk = 0; kk < 2; ++kk){
          int c = (2*h2 + kk)*16 + cl;
          unsafeAtomicAdd(&a_s[cur*C + c],       ms[kk]);
          unsafeAtomicAdd(&a_v[(cur*3+0)*C + c], mv0[kk]);
          unsafeAtomicAdd(&a_v[(cur*3+1)*C + c], mv1[kk]);
          unsafeAtomicAdd(&a_v[(cur*3+2)*C + c], mv2[kk]);
          ms[kk]=0.f; mv0[kk]=0.f; mv1[kk]=0.f; mv2[kk]=0.f;
        }
        cur = rc;
      }
      float u0 = uxB[i], u1 = uyB[i], u2 = uzB[i];
      #pragma unroll
      for (int kk = 0; kk < 2; ++kk){
        float se  = bf2f(gvB[i][kk].x);
        float ve0 = bf2f(gvB[i][kk].y);
        float ve1 = bf2f(gvB[i][kk].z);
        float ve2 = bf2f(gvB[i][kk].w);
        float w0 = accB[0*2+kk][i];
        float w1 = accB[1*2+kk][i];
        float w2 = accB[2*2+kk][i];
        float w3 = accB[3*2+kk][i];
        float w4 = accB[4*2+kk][i];
        float dt  = ve0*u0 + ve1*u1 + ve2*u2;
        float cr0 = ve1*u2 - ve2*u1;
        float cr1 = ve2*u0 - ve0*u2;
        float cr2 = ve0*u1 - ve1*u0;
        ms[kk]  += w0*se + w3*dt;
        mv0[kk] += w1*ve0 + w2*u0 + w4*cr0;
        mv1[kk] += w1*ve1 + w2*u1 + w4*cr1;
        mv2[kk] += w1*ve2 + w2*u2 + w4*cr2;
      }
    }
    #pragma unroll
    for (int kk = 0; kk < 2; ++kk){
      int c = (2*h2 + kk)*16 + cl;
      unsafeAtomicAdd(&a_s[cur*C + c],       ms[kk]);
      unsafeAtomicAdd(&a_v[(cur*3+0)*C + c], mv0[kk]);
      unsafeAtomicAdd(&a_v[(cur*3+1)*C + c], mv1[kk]);
      unsafeAtomicAdd(&a_v[(cur*3+2)*C + c], mv2[kk]);
    }
  }
}

// ---------------- K3: down-matvec, product basis, soft-norm, residual, readout (4/blk)
__global__ __launch_bounds__(256) void node_post_kernel(
    const float* __restrict__ a_s, const float* __restrict__ a_v,
    const float* __restrict__ fs_in, const float* __restrict__ fv_in,
    const int* __restrict__ species,
    const float* __restrict__ W_rs, const float* __restrict__ W_rv,
    const float* __restrict__ W_ds, const float* __restrict__ W_dv,
    const float* __restrict__ w1s, const float* __restrict__ w1v,
    const float* __restrict__ w2ss, const float* __restrict__ w2vv, const float* __restrict__ w2sv,
    const float* __restrict__ W_ps, const float* __restrict__ W_pv,
    const float* __restrict__ w_read, float* __restrict__ out)
{
  const int ni = threadIdx.x >> 6;
  const int d  = threadIdx.x & 63;
  const int n  = blockIdx.x*4 + ni;
  const int sp = species[n];
  __shared__ float as_l[4][C];
  __shared__ float av_l[4][3][C];
  __shared__ float si_l[4][C];
  __shared__ float vi_l[4][3][C];
  as_l[ni][d] = a_s[n*C + d];
  #pragma unroll
  for (int x=0;x<3;x++) av_l[ni][x][d] = a_v[(n*3+x)*C + d];
  si_l[ni][d] = fs_in[n*C + d];
  #pragma unroll
  for (int x=0;x<3;x++) vi_l[ni][x][d] = fv_in[(n*C + d)*3 + x];
  __syncthreads();
  const float* Wrs_p = W_rs + sp*C*C;
  const float* Wrv_p = W_rv + sp*C*C;
  float bs=0, bv0=0, bv1=0, bv2=0, rs=0, rv0=0, rv1=0, rv2=0;
  for (int c=0;c<C;++c){
    float wds = W_ds[c*C+d], wdv = W_dv[c*C+d];
    float wrs = Wrs_p[c*C+d], wrv = Wrv_p[c*C+d];
    bs  += as_l[ni][c]*wds;
    bv0 += av_l[ni][0][c]*wdv; bv1 += av_l[ni][1][c]*wdv; bv2 += av_l[ni][2][c]*wdv;
    rs  += si_l[ni][c]*wrs;
    rv0 += vi_l[ni][0][c]*wrv; rv1 += vi_l[ni][1][c]*wrv; rv2 += vi_l[ni][2][c]*wrv;
  }
  float vv = bv0*bv0 + bv1*bv1 + bv2*bv2;
  float ps  = w1s[sp*C+d]*bs + w2ss[sp*C+d]*bs*bs + w2vv[sp*C+d]*vv;
  float c1v = w1v[sp*C+d], c2sv = w2sv[sp*C+d];
  float pv0 = c1v*bv0 + c2sv*bs*bv0;
  float pv1 = c1v*bv1 + c2sv*bs*bv1;
  float pv2 = c1v*bv2 + c2sv*bs*bv2;
  __syncthreads();
  as_l[ni][d] = ps; av_l[ni][0][d]=pv0; av_l[ni][1][d]=pv1; av_l[ni][2][d]=pv2;
  __syncthreads();
  float qs=0, qv0=0, qv1=0, qv2=0;
  for (int c=0;c<C;++c){
    float wps = W_ps[c*C+d], wpv = W_pv[c*C+d];
    qs  += as_l[ni][c]*wps;
    qv0 += av_l[ni][0][c]*wpv; qv1 += av_l[ni][1][c]*wpv; qv2 += av_l[ni][2][c]*wpv;
  }
  float fsv = qs * phi_f(fabsf(qs)) + rs;
  float nv = sqrtf(qv0*qv0 + qv1*qv1 + qv2*qv2);
  float ph = phi_f(nv);
  float fv0 = qv0*ph + rv0;
  float fv1 = qv1*ph + rv1;
  float fv2 = qv2*ph + rv2;
  out[FS_OFF + n*C + d] = fsv;
  float* fvo = &out[FV_OFF + (size_t)(n*C + d)*3];
  fvo[0]=fv0; fvo[1]=fv1; fvo[2]=fv2;
  #pragma unroll
  for (int h=0; h<HEADS; ++h){
    float r = fsv * w_read[h*C + d];
    #pragma unroll
    for (int off=32; off>0; off>>=1) r += __shfl_down(r, off);
    if (d == 0) out[n*HEADS + h] = r;
  }
}

extern "C" void kernel_launch(void* const* d_in, const int* in_sizes, int n_in,
                              void* d_out, int out_size, void* d_ws, size_t ws_size,
                              hipStream_t stream)
{
  const float* ev   = (const float*)d_in[0];
  const float* nfs  = (const float*)d_in[1];
  const float* nfv  = (const float*)d_in[2];
  const float* re   = (const float*)d_in[3];
  const int*   spec = (const int*)d_in[4];
  const int*   snd  = (const int*)d_in[5];
  const int*   rcv  = (const int*)d_in[6];
  const float* W_rs = (const float*)d_in[7];
  const float* W_rv = (const float*)d_in[8];
  const float* Wus  = (const float*)d_in[9];
  const float* Wuv  = (const float*)d_in[10];
  const float* Wr1  = (const float*)d_in[11];
  const float* Wr2  = (const float*)d_in[12];
  const float* Wds  = (const float*)d_in[13];
  const float* Wdv  = (const float*)d_in[14];
  const float* w1s  = (const float*)d_in[15];
  const float* w1v  = (const float*)d_in[16];
  const float* w2ss = (const float*)d_in[17];
  const float* w2vv = (const float*)d_in[18];
  const float* w2sv = (const float*)d_in[19];
  const float* Wps  = (const float*)d_in[20];
  const float* Wpv  = (const float*)d_in[21];
  const float* wrd  = (const float*)d_in[22];

  float* out = (float*)d_out;
  float* ws  = (float*)d_ws;
  // ws layout (f32 units) — r8 proven layout
  ushort4* suv  = (ushort4*)ws;            // 2,560,000 f32-equiv (10.24 MB)
  float*   a_s  = ws + 2560000;            // 1,280,000
  float*   a_v  = ws + 3840000;            // 3,840,000
  int*    count = (int*)(ws + 7680000);    // 20,000
  int*    cursr = (int*)(ws + 7700000);    // 20,000
  int*    snd_s = (int*)(ws + 7720000);    // 320,000
  int*    rcv_s = (int*)(ws + 8040000);    // 320,000
  float4* u_s   = (float4*)(ws + 8360000); // 1,280,000 f32 (16 B/edge)
  float*  re_s  = ws + 9640000;            // 2,560,000
  unsigned short* wr2t = (unsigned short*)(ws + 12200000);  // 20,480 bf16

  hipMemsetAsync(a_s, 0, (size_t)5120000*sizeof(float), stream);   // a_s + a_v
  hipMemsetAsync(count, 0, (size_t)N_NODES*sizeof(int), stream);

  wr2t_kernel<<<(320*64)/256, 256, 0, stream>>>(Wr2, wr2t);
  node_up_kernel<<<N_NODES/4, 256, 0, stream>>>(nfs, nfv, Wus, Wuv, suv);
  hist_kernel<<<E_EDGES/256, 256, 0, stream>>>(rcv, count);
  scan_kernel<<<1, 1024, 0, stream>>>(count, cursr);
  scatter_kernel<<<E_EDGES/256, 256, 0, stream>>>(snd, rcv, ev, re, cursr,
                                                  snd_s, rcv_s, u_s, re_s);
  edge_kernel<<<NPAIR, 512, 0, stream>>>(u_s, re_s, snd_s, rcv_s, Wr1, wr2t,
                                         suv, a_s, a_v);
  node_post_kernel<<<N_NODES/4, 256, 0, stream>>>(a_s, a_v, nfs, nfv, spec,
      W_rs, W_rv, Wds, Wdv, w1s, w1v, w2ss, w2vv, w2sv, Wps, Wpv, wrd, out);
}

// Round 12
// 392.879 us; speedup vs baseline: 1.1058x; 1.0176x over previous
//
#include <hip/hip_runtime.h>

#define N_NODES 20000
#define C 64
#define E_EDGES 320000
#define S_SPEC 64
#define R_DIM 8
#define HR 64
#define HEADS 2
#define TE 64
#define NPAIR (E_EDGES/128)      // 2500 blocks, 2 tiles (128 edges) each
#define HPAD 68                  // padded bf16 row stride (k-dim)
#define INV_AVG (1.0f/16.0f)

// out layout: node_out [0,40000) ; f_s [40000, 1320000) ; f_v [1320000, 5160000)
#define FS_OFF 40000
#define FV_OFF 1320000

typedef short bf16x4 __attribute__((ext_vector_type(4)));
typedef float f32x4  __attribute__((ext_vector_type(4)));

__device__ __forceinline__ unsigned short f2bf(float f){
  unsigned u = __float_as_uint(f);
  u += 0x7fffu + ((u >> 16) & 1u);
  return (unsigned short)(u >> 16);
}
__device__ __forceinline__ float bf2f(unsigned short b){
  return __uint_as_float(((unsigned)b) << 16);
}
__device__ __forceinline__ unsigned packbf(float a, float b){
  return (unsigned)f2bf(a) | ((unsigned)f2bf(b) << 16);
}
__device__ __forceinline__ float unplo(unsigned u){ return __uint_as_float(u << 16); }
__device__ __forceinline__ float unphi(unsigned u){ return __uint_as_float(u & 0xffff0000u); }
__device__ __forceinline__ float phi_f(float x){
  float n = x * 0.5f;
  float s = (n > 0.0f) ? expf(-1.0f/n) : 0.0f;
  return 1.0f / (1.0f + n * s);
}

// ---------------- prep A: Wr2T[n][k] = bf16(Wr2[k][n] / AVG)  (320x64) ----------------
__global__ __launch_bounds__(256) void wr2t_kernel(const float* __restrict__ Wr2,
                                                   unsigned short* __restrict__ wr2t){
  int idx = blockIdx.x*256 + threadIdx.x;      // n*64 + k
  int n = idx >> 6, k = idx & 63;
  wr2t[idx] = f2bf(Wr2[k*320 + n] * INV_AVG);
}

// ---------------- prep B: packed bf16-pair weight tables ------------------------------
// wrp[sp*4096 + c*64 + d] = {W_rs, W_rv} ; wdp = {W_ds, W_dv} ; wpp = {W_ps, W_pv} ;
// wup = {W_up_s, W_up_v}. Total 262144 + 3*4096 elements.
__global__ __launch_bounds__(256) void wpack_kernel(
    const float* __restrict__ W_rs, const float* __restrict__ W_rv,
    const float* __restrict__ W_ds, const float* __restrict__ W_dv,
    const float* __restrict__ W_ps, const float* __restrict__ W_pv,
    const float* __restrict__ Wus,  const float* __restrict__ Wuv,
    unsigned* __restrict__ wrp, unsigned* __restrict__ wdp,
    unsigned* __restrict__ wpp, unsigned* __restrict__ wup){
  int idx = blockIdx.x*256 + threadIdx.x;
  if (idx < S_SPEC*C*C){
    wrp[idx] = packbf(W_rs[idx], W_rv[idx]);
  } else {
    int r = idx - S_SPEC*C*C;          // 0 .. 3*4096-1
    int which = r >> 12, e = r & 4095;
    if (which == 0)      wdp[e] = packbf(W_ds[e], W_dv[e]);
    else if (which == 1) wpp[e] = packbf(W_ps[e], W_pv[e]);
    else                 wup[e] = packbf(Wus[e],  Wuv[e]);
  }
}

// ---------------- K1: up-projection w/ LDS packed weights; writes packed bf16 suv -----
__global__ __launch_bounds__(256) void node_up_kernel(
    const float* __restrict__ fs, const float* __restrict__ fv,
    const unsigned* __restrict__ wup,
    ushort4* __restrict__ suv){
  const int ni = threadIdx.x >> 6;
  const int d  = threadIdx.x & 63;
  const int n  = blockIdx.x*4 + ni;
  __shared__ float s_l[4][C];
  __shared__ float v_l[4][3][C];
  __shared__ unsigned wup_l[C*C];      // 16 KB
  const int t = threadIdx.x;
  #pragma unroll
  for (int j = 0; j < 16; ++j) wup_l[t + 256*j] = wup[t + 256*j];
  s_l[ni][d] = fs[n*C + d];
  #pragma unroll
  for (int x = 0; x < 3; ++x) v_l[ni][x][d] = fv[(n*C + d)*3 + x];
  __syncthreads();
  float as = 0.f, a0 = 0.f, a1 = 0.f, a2 = 0.f;
  #pragma unroll 4
  for (int c = 0; c < C; ++c){
    unsigned u = wup_l[c*C + d];
    float wsv = unplo(u);
    float wvv = unphi(u);
    as += s_l[ni][c] * wsv;
    a0 += v_l[ni][0][c] * wvv;
    a1 += v_l[ni][1][c] * wvv;
    a2 += v_l[ni][2][c] * wvv;
  }
  ushort4 o;
  o.x = f2bf(as); o.y = f2bf(a0); o.z = f2bf(a1); o.w = f2bf(a2);
  suv[(size_t)n*C + d] = o;
}

// ---------------- sort pass A: histogram of receivers ---------------------------------
__global__ __launch_bounds__(256) void hist_kernel(const int* __restrict__ rcv, int* __restrict__ count){
  int e = blockIdx.x*256 + threadIdx.x;
  atomicAdd(&count[rcv[e]], 1);
}

// ---------------- sort pass B: exclusive scan over 20000 counts (1 block) -------------
__global__ __launch_bounds__(1024) void scan_kernel(const int* __restrict__ count, int* __restrict__ cursor){
  __shared__ int sums[1024];
  const int t = threadIdx.x;
  const int base = t*20;
  int s = 0;
  #pragma unroll 4
  for (int i = 0; i < 20; ++i){ int idx = base+i; if (idx < N_NODES) s += count[idx]; }
  sums[t] = s;
  __syncthreads();
  for (int off = 1; off < 1024; off <<= 1){
    int v = (t >= off) ? sums[t-off] : 0;
    __syncthreads();
    sums[t] += v;
    __syncthreads();
  }
  int run = (t > 0) ? sums[t-1] : 0;
  for (int i = 0; i < 20; ++i){
    int idx = base+i;
    if (idx < N_NODES){ cursor[idx] = run; run += count[idx]; }
  }
}

// ---------------- sort pass C: scatter into sorted arrays, u pre-normalized ----------
__global__ __launch_bounds__(256) void scatter_kernel(
    const int* __restrict__ snd, const int* __restrict__ rcv,
    const float* __restrict__ ev, const float* __restrict__ re,
    int* __restrict__ cursor,
    int* __restrict__ snd_s, int* __restrict__ rcv_s,
    float4* __restrict__ u_s, float* __restrict__ re_s){
  int e = blockIdx.x*256 + threadIdx.x;
  int r = rcv[e];
  int pos = atomicAdd(&cursor[r], 1);
  snd_s[pos] = snd[e];
  rcv_s[pos] = r;
  float x = ev[e*3+0], y = ev[e*3+1], z = ev[e*3+2];
  float nr = sqrtf(x*x + y*y + z*z);
  float inv = 1.0f / fmaxf(nr, 1e-9f);
  float4 u4; u4.x = x*inv; u4.y = y*inv; u4.z = z*inv; u4.w = 0.f;
  u_s[pos] = u4;
  const float4* rp = (const float4*)&re[(size_t)e*R_DIM];
  float4 ra = rp[0], rb = rp[1];
  float4* op = (float4*)&re_s[(size_t)pos*R_DIM];
  op[0] = ra; op[1] = rb;
}

// ---------------- K2: MFMA radial GEMM, 2-tile software pipeline (r11, frozen) --------
__global__ __launch_bounds__(512, 4) void edge_kernel(
    const float4* __restrict__ u_s, const float* __restrict__ re_s,
    const int* __restrict__ snd_s, const int* __restrict__ rcv_s,
    const float* __restrict__ Wr1, const unsigned short* __restrict__ wr2t,
    const ushort4* __restrict__ suv,
    float* __restrict__ a_s, float* __restrict__ a_v)
{
  __shared__ __align__(16) float Wr1_l[R_DIM*HR];            // 2 KB
  __shared__ __align__(16) unsigned short Wr2T_l[320*HPAD];  // 43.5 KB

  const int t = threadIdx.x;
  const int lane = t & 63;
  const int w = t >> 6;
  const int g  = w >> 1;
  const int h2 = w & 1;
  int b = blockIdx.x;
  int xcd = b & 7, idx = b >> 3;
  const int q = NPAIR >> 3, r = NPAIR & 7;
  int pair = (xcd < r ? xcd*(q+1) : r*(q+1) + (xcd-r)*q) + idx;
  const int e0A = pair * 128;
  const int e0B = e0A + 64;

  Wr1_l[t] = Wr1[t];
  #pragma unroll
  for (int j = 0; j < 10; ++j){
    int i4 = t + 512*j;
    ushort4 v4 = ((const ushort4*)wr2t)[i4];
    int el = i4*4; int n = el >> 6, k = el & 63;
    *(ushort4*)&Wr2T_l[n*HPAD + k] = v4;
  }

  const int arow = g*16 + (lane & 15);
  const int koff = 4*(lane >> 4);
  const int cl = lane & 15;
  const int ebase = g*16 + (lane >> 4)*4;

  float4 raA = ((const float4*)&re_s[(size_t)(e0A + arow)*R_DIM])[0];
  float4 rbA = ((const float4*)&re_s[(size_t)(e0A + arow)*R_DIM])[1];
  float uxA[4], uyA[4], uzA[4]; int snA[4], rcA[4];
  #pragma unroll
  for (int i = 0; i < 4; ++i){
    int e = e0A + ebase + i;
    float4 uu = u_s[e];
    uxA[i]=uu.x; uyA[i]=uu.y; uzA[i]=uu.z;
    snA[i]=snd_s[e]; rcA[i]=rcv_s[e];
  }
  ushort4 gvA[4][2];
  #pragma unroll
  for (int i = 0; i < 4; ++i){
    const ushort4* sp_ = &suv[(size_t)snA[i]*C];
    #pragma unroll
    for (int kk = 0; kk < 2; ++kk) gvA[i][kk] = sp_[(2*h2 + kk)*16 + cl];
  }
  __syncthreads();

  bf16x4 haA[4];
  #pragma unroll
  for (int kt = 0; kt < 4; ++kt){
    short4 tmp;
    #pragma unroll
    for (int j = 0; j < 4; ++j){
      int k = kt*16 + koff + j;
      float acc = raA.x*Wr1_l[0*HR+k] + raA.y*Wr1_l[1*HR+k] + raA.z*Wr1_l[2*HR+k] + raA.w*Wr1_l[3*HR+k]
                + rbA.x*Wr1_l[4*HR+k] + rbA.y*Wr1_l[5*HR+k] + rbA.z*Wr1_l[6*HR+k] + rbA.w*Wr1_l[7*HR+k];
      float sil = acc / (1.0f + expf(-acc));
      ((unsigned short*)&tmp)[j] = f2bf(sil);
    }
    haA[kt] = *(bf16x4*)&tmp;
  }

  float4 raB = ((const float4*)&re_s[(size_t)(e0B + arow)*R_DIM])[0];
  float4 rbB = ((const float4*)&re_s[(size_t)(e0B + arow)*R_DIM])[1];
  float uxB[4], uyB[4], uzB[4]; int snB[4], rcB[4];
  #pragma unroll
  for (int i = 0; i < 4; ++i){
    int e = e0B + ebase + i;
    float4 uu = u_s[e];
    uxB[i]=uu.x; uyB[i]=uu.y; uzB[i]=uu.z;
    snB[i]=snd_s[e]; rcB[i]=rcv_s[e];
  }

  f32x4 accA[10];
  #pragma unroll
  for (int lf = 0; lf < 10; ++lf) accA[lf] = (f32x4){0.f,0.f,0.f,0.f};
  #pragma unroll
  for (int kt = 0; kt < 4; ++kt){
    bf16x4 af = haA[kt];
    #pragma unroll
    for (int lf = 0; lf < 10; ++lf){
      int p = lf >> 1, kk = lf & 1;
      int n = (p*4 + 2*h2 + kk)*16 + cl;
      bf16x4 bf = *(const bf16x4*)&Wr2T_l[n*HPAD + kt*16 + koff];
      accA[lf] = __builtin_amdgcn_mfma_f32_16x16x16bf16_1k(af, bf, accA[lf], 0, 0, 0);
    }
  }

  ushort4 gvB[4][2];
  #pragma unroll
  for (int i = 0; i < 4; ++i){
    const ushort4* sp_ = &suv[(size_t)snB[i]*C];
    #pragma unroll
    for (int kk = 0; kk < 2; ++kk) gvB[i][kk] = sp_[(2*h2 + kk)*16 + cl];
  }

  {
    float ms[2], mv0[2], mv1[2], mv2[2];
    #pragma unroll
    for (int kk = 0; kk < 2; ++kk){ ms[kk]=0.f; mv0[kk]=0.f; mv1[kk]=0.f; mv2[kk]=0.f; }
    int cur = rcA[0];
    #pragma unroll
    for (int i = 0; i < 4; ++i){
      int rc = rcA[i];
      if (rc != cur){
        #pragma unroll
        for (int kk = 0; kk < 2; ++kk){
          int c = (2*h2 + kk)*16 + cl;
          unsafeAtomicAdd(&a_s[cur*C + c],       ms[kk]);
          unsafeAtomicAdd(&a_v[(cur*3+0)*C + c], mv0[kk]);
          unsafeAtomicAdd(&a_v[(cur*3+1)*C + c], mv1[kk]);
          unsafeAtomicAdd(&a_v[(cur*3+2)*C + c], mv2[kk]);
          ms[kk]=0.f; mv0[kk]=0.f; mv1[kk]=0.f; mv2[kk]=0.f;
        }
        cur = rc;
      }
      float u0 = uxA[i], u1 = uyA[i], u2 = uzA[i];
      #pragma unroll
      for (int kk = 0; kk < 2; ++kk){
        float se  = bf2f(gvA[i][kk].x);
        float ve0 = bf2f(gvA[i][kk].y);
        float ve1 = bf2f(gvA[i][kk].z);
        float ve2 = bf2f(gvA[i][kk].w);
        float w0 = accA[0*2+kk][i];
        float w1 = accA[1*2+kk][i];
        float w2 = accA[2*2+kk][i];
        float w3 = accA[3*2+kk][i];
        float w4 = accA[4*2+kk][i];
        float dt  = ve0*u0 + ve1*u1 + ve2*u2;
        float cr0 = ve1*u2 - ve2*u1;
        float cr1 = ve2*u0 - ve0*u2;
        float cr2 = ve0*u1 - ve1*u0;
        ms[kk]  += w0*se + w3*dt;
        mv0[kk] += w1*ve0 + w2*u0 + w4*cr0;
        mv1[kk] += w1*ve1 + w2*u1 + w4*cr1;
        mv2[kk] += w1*ve2 + w2*u2 + w4*cr2;
      }
    }
    #pragma unroll
    for (int kk = 0; kk < 2; ++kk){
      int c = (2*h2 + kk)*16 + cl;
      unsafeAtomicAdd(&a_s[cur*C + c],       ms[kk]);
      unsafeAtomicAdd(&a_v[(cur*3+0)*C + c], mv0[kk]);
      unsafeAtomicAdd(&a_v[(cur*3+1)*C + c], mv1[kk]);
      unsafeAtomicAdd(&a_v[(cur*3+2)*C + c], mv2[kk]);
    }
  }

  bf16x4 haB[4];
  #pragma unroll
  for (int kt = 0; kt < 4; ++kt){
    short4 tmp;
    #pragma unroll
    for (int j = 0; j < 4; ++j){
      int k = kt*16 + koff + j;
      float acc = raB.x*Wr1_l[0*HR+k] + raB.y*Wr1_l[1*HR+k] + raB.z*Wr1_l[2*HR+k] + raB.w*Wr1_l[3*HR+k]
                + rbB.x*Wr1_l[4*HR+k] + rbB.y*Wr1_l[5*HR+k] + rbB.z*Wr1_l[6*HR+k] + rbB.w*Wr1_l[7*HR+k];
      float sil = acc / (1.0f + expf(-acc));
      ((unsigned short*)&tmp)[j] = f2bf(sil);
    }
    haB[kt] = *(bf16x4*)&tmp;
  }
  f32x4 accB[10];
  #pragma unroll
  for (int lf = 0; lf < 10; ++lf) accB[lf] = (f32x4){0.f,0.f,0.f,0.f};
  #pragma unroll
  for (int kt = 0; kt < 4; ++kt){
    bf16x4 af = haB[kt];
    #pragma unroll
    for (int lf = 0; lf < 10; ++lf){
      int p = lf >> 1, kk = lf & 1;
      int n = (p*4 + 2*h2 + kk)*16 + cl;
      bf16x4 bf = *(const bf16x4*)&Wr2T_l[n*HPAD + kt*16 + koff];
      accB[lf] = __builtin_amdgcn_mfma_f32_16x16x16bf16_1k(af, bf, accB[lf], 0, 0, 0);
    }
  }

  {
    float ms[2], mv0[2], mv1[2], mv2[2];
    #pragma unroll
    for (int kk = 0; kk < 2; ++kk){ ms[kk]=0.f; mv0[kk]=0.f; mv1[kk]=0.f; mv2[kk]=0.f; }
    int cur = rcB[0];
    #pragma unroll
    for (int i = 0; i < 4; ++i){
      int rc = rcB[i];
      if (rc != cur){
        #pragma unroll
        for (int kk = 0; kk < 2; ++kk){
          int c = (2*h2 + kk)*16 + cl;
          unsafeAtomicAdd(&a_s[cur*C + c],       ms[kk]);
          unsafeAtomicAdd(&a_v[(cur*3+0)*C + c], mv0[kk]);
          unsafeAtomicAdd(&a_v[(cur*3+1)*C + c], mv1[kk]);
          unsafeAtomicAdd(&a_v[(cur*3+2)*C + c], mv2[kk]);
          ms[kk]=0.f; mv0[kk]=0.f; mv1[kk]=0.f; mv2[kk]=0.f;
        }
        cur = rc;
      }
      float u0 = uxB[i], u1 = uyB[i], u2 = uzB[i];
      #pragma unroll
      for (int kk = 0; kk < 2; ++kk){
        float se  = bf2f(gvB[i][kk].x);
        float ve0 = bf2f(gvB[i][kk].y);
        float ve1 = bf2f(gvB[i][kk].z);
        float ve2 = bf2f(gvB[i][kk].w);
        float w0 = accB[0*2+kk][i];
        float w1 = accB[1*2+kk][i];
        float w2 = accB[2*2+kk][i];
        float w3 = accB[3*2+kk][i];
        float w4 = accB[4*2+kk][i];
        float dt  = ve0*u0 + ve1*u1 + ve2*u2;
        float cr0 = ve1*u2 - ve2*u1;
        float cr1 = ve2*u0 - ve0*u2;
        float cr2 = ve0*u1 - ve1*u0;
        ms[kk]  += w0*se + w3*dt;
        mv0[kk] += w1*ve0 + w2*u0 + w4*cr0;
        mv1[kk] += w1*ve1 + w2*u1 + w4*cr1;
        mv2[kk] += w1*ve2 + w2*u2 + w4*cr2;
      }
    }
    #pragma unroll
    for (int kk = 0; kk < 2; ++kk){
      int c = (2*h2 + kk)*16 + cl;
      unsafeAtomicAdd(&a_s[cur*C + c],       ms[kk]);
      unsafeAtomicAdd(&a_v[(cur*3+0)*C + c], mv0[kk]);
      unsafeAtomicAdd(&a_v[(cur*3+1)*C + c], mv1[kk]);
      unsafeAtomicAdd(&a_v[(cur*3+2)*C + c], mv2[kk]);
    }
  }
}

// ---------------- K3: node_post with LDS packed weights -------------------------------
__global__ __launch_bounds__(256) void node_post_kernel(
    const float* __restrict__ a_s, const float* __restrict__ a_v,
    const float* __restrict__ fs_in, const float* __restrict__ fv_in,
    const int* __restrict__ species,
    const unsigned* __restrict__ wrp,       // {W_rs,W_rv} per species, L2
    const unsigned* __restrict__ wdp,       // {W_ds,W_dv}
    const unsigned* __restrict__ wpp,       // {W_ps,W_pv}
    const float* __restrict__ w1s, const float* __restrict__ w1v,
    const float* __restrict__ w2ss, const float* __restrict__ w2vv, const float* __restrict__ w2sv,
    const float* __restrict__ w_read, float* __restrict__ out)
{
  const int ni = threadIdx.x >> 6;
  const int d  = threadIdx.x & 63;
  const int n  = blockIdx.x*4 + ni;
  const int sp = species[n];
  const int t  = threadIdx.x;
  __shared__ float as_l[4][C];
  __shared__ float av_l[4][3][C];
  __shared__ float si_l[4][C];
  __shared__ float vi_l[4][3][C];
  __shared__ unsigned wdp_l[C*C];   // 16 KB
  __shared__ unsigned wpp_l[C*C];   // 16 KB
  #pragma unroll
  for (int j = 0; j < 16; ++j){
    wdp_l[t + 256*j] = wdp[t + 256*j];
    wpp_l[t + 256*j] = wpp[t + 256*j];
  }
  as_l[ni][d] = a_s[n*C + d];
  #pragma unroll
  for (int x=0;x<3;x++) av_l[ni][x][d] = a_v[(n*3+x)*C + d];
  si_l[ni][d] = fs_in[n*C + d];
  #pragma unroll
  for (int x=0;x<3;x++) vi_l[ni][x][d] = fv_in[(n*C + d)*3 + x];
  __syncthreads();
  const unsigned* wrp_p = wrp + (size_t)sp*C*C;
  float bs=0, bv0=0, bv1=0, bv2=0, rs=0, rv0=0, rv1=0, rv2=0;
  #pragma unroll 4
  for (int c=0;c<C;++c){
    unsigned ud = wdp_l[c*C+d];
    unsigned ur = wrp_p[c*C+d];
    float wds = unplo(ud), wdv = unphi(ud);
    float wrs = unplo(ur), wrv = unphi(ur);
    bs  += as_l[ni][c]*wds;
    bv0 += av_l[ni][0][c]*wdv; bv1 += av_l[ni][1][c]*wdv; bv2 += av_l[ni][2][c]*wdv;
    rs  += si_l[ni][c]*wrs;
    rv0 += vi_l[ni][0][c]*wrv; rv1 += vi_l[ni][1][c]*wrv; rv2 += vi_l[ni][2][c]*wrv;
  }
  float vv = bv0*bv0 + bv1*bv1 + bv2*bv2;
  float ps  = w1s[sp*C+d]*bs + w2ss[sp*C+d]*bs*bs + w2vv[sp*C+d]*vv;
  float c1v = w1v[sp*C+d], c2sv = w2sv[sp*C+d];
  float pv0 = c1v*bv0 + c2sv*bs*bv0;
  float pv1 = c1v*bv1 + c2sv*bs*bv1;
  float pv2 = c1v*bv2 + c2sv*bs*bv2;
  __syncthreads();
  as_l[ni][d] = ps; av_l[ni][0][d]=pv0; av_l[ni][1][d]=pv1; av_l[ni][2][d]=pv2;
  __syncthreads();
  float qs=0, qv0=0, qv1=0, qv2=0;
  #pragma unroll 4
  for (int c=0;c<C;++c){
    unsigned up = wpp_l[c*C+d];
    float wps = unplo(up), wpv = unphi(up);
    qs  += as_l[ni][c]*wps;
    qv0 += av_l[ni][0][c]*wpv; qv1 += av_l[ni][1][c]*wpv; qv2 += av_l[ni][2][c]*wpv;
  }
  float fsv = qs * phi_f(fabsf(qs)) + rs;
  float nv = sqrtf(qv0*qv0 + qv1*qv1 + qv2*qv2);
  float ph = phi_f(nv);
  float fv0 = qv0*ph + rv0;
  float fv1 = qv1*ph + rv1;
  float fv2 = qv2*ph + rv2;
  out[FS_OFF + n*C + d] = fsv;
  float* fvo = &out[FV_OFF + (size_t)(n*C + d)*3];
  fvo[0]=fv0; fvo[1]=fv1; fvo[2]=fv2;
  #pragma unroll
  for (int h=0; h<HEADS; ++h){
    float r = fsv * w_read[h*C + d];
    #pragma unroll
    for (int off=32; off>0; off>>=1) r += __shfl_down(r, off);
    if (d == 0) out[n*HEADS + h] = r;
  }
}

extern "C" void kernel_launch(void* const* d_in, const int* in_sizes, int n_in,
                              void* d_out, int out_size, void* d_ws, size_t ws_size,
                              hipStream_t stream)
{
  const float* ev   = (const float*)d_in[0];
  const float* nfs  = (const float*)d_in[1];
  const float* nfv  = (const float*)d_in[2];
  const float* re   = (const float*)d_in[3];
  const int*   spec = (const int*)d_in[4];
  const int*   snd  = (const int*)d_in[5];
  const int*   rcv  = (const int*)d_in[6];
  const float* W_rs = (const float*)d_in[7];
  const float* W_rv = (const float*)d_in[8];
  const float* Wus  = (const float*)d_in[9];
  const float* Wuv  = (const float*)d_in[10];
  const float* Wr1  = (const float*)d_in[11];
  const float* Wr2  = (const float*)d_in[12];
  const float* Wds  = (const float*)d_in[13];
  const float* Wdv  = (const float*)d_in[14];
  const float* w1s  = (const float*)d_in[15];
  const float* w1v  = (const float*)d_in[16];
  const float* w2ss = (const float*)d_in[17];
  const float* w2vv = (const float*)d_in[18];
  const float* w2sv = (const float*)d_in[19];
  const float* Wps  = (const float*)d_in[20];
  const float* Wpv  = (const float*)d_in[21];
  const float* wrd  = (const float*)d_in[22];

  float* out = (float*)d_out;
  float* ws  = (float*)d_ws;
  // ws layout (f32 units)
  ushort4* suv  = (ushort4*)ws;            // 2,560,000 f32-equiv (10.24 MB)
  float*   a_s  = ws + 2560000;            // 1,280,000
  float*   a_v  = ws + 3840000;            // 3,840,000
  int*    count = (int*)(ws + 7680000);    // 20,000
  int*    cursr = (int*)(ws + 7700000);    // 20,000
  int*    snd_s = (int*)(ws + 7720000);    // 320,000
  int*    rcv_s = (int*)(ws + 8040000);    // 320,000
  float4* u_s   = (float4*)(ws + 8360000); // 1,280,000 f32 (16 B/edge)
  float*  re_s  = ws + 9640000;            // 2,560,000 -> 12,200,000
  unsigned short* wr2t = (unsigned short*)(ws + 12200000);  // 10,240 f32 -> 12,210,240
  unsigned* wrp = (unsigned*)(ws + 12210240);  // 262,144 -> 12,472,384
  unsigned* wdp = (unsigned*)(ws + 12472384);  // 4,096  -> 12,476,480
  unsigned* wpp = (unsigned*)(ws + 12476480);  // 4,096  -> 12,480,576
  unsigned* wup = (unsigned*)(ws + 12480576);  // 4,096  -> 12,484,672

  hipMemsetAsync(a_s, 0, (size_t)5120000*sizeof(float), stream);   // a_s + a_v
  hipMemsetAsync(count, 0, (size_t)N_NODES*sizeof(int), stream);

  wr2t_kernel<<<(320*64)/256, 256, 0, stream>>>(Wr2, wr2t);
  wpack_kernel<<<(S_SPEC*C*C + 3*C*C)/256, 256, 0, stream>>>(
      W_rs, W_rv, Wds, Wdv, Wps, Wpv, Wus, Wuv, wrp, wdp, wpp, wup);
  node_up_kernel<<<N_NODES/4, 256, 0, stream>>>(nfs, nfv, wup, suv);
  hist_kernel<<<E_EDGES/256, 256, 0, stream>>>(rcv, count);
  scan_kernel<<<1, 1024, 0, stream>>>(count, cursr);
  scatter_kernel<<<E_EDGES/256, 256, 0, stream>>>(snd, rcv, ev, re, cursr,
                                                  snd_s, rcv_s, u_s, re_s);
  edge_kernel<<<NPAIR, 512, 0, stream>>>(u_s, re_s, snd_s, rcv_s, Wr1, wr2t,
                                         suv, a_s, a_v);
  node_post_kernel<<<N_NODES/4, 256, 0, stream>>>(a_s, a_v, nfs, nfv, spec,
      wrp, wdp, wpp, w1s, w1v, w2ss, w2vv, w2sv, wrd, out);
}